// Round 11
// baseline (44.713 us; speedup 1.0000x reference)
//
#include <hip/hip_runtime.h>

#define NROW 8192
#define MDIM 128
#define KLAB 16
#define NSLAB 64                     // 8192 / 128 supertile rows
#define NSUPER (NSLAB*(NSLAB+1)/2)   // 2080 upper-tri supertiles
#define NBLK (NSUPER*2)              // 4160 half-tile blocks (64 rows x 128 cols)
#define MARGINP  16.970562748477139f // 1.5 * sqrt(128): margin pre-scaled (defer /sqrt(128))
#define MARGINP2 288.0f              // MARGINP^2 exactly

typedef __attribute__((ext_vector_type(8))) short  s16x8;
typedef __attribute__((ext_vector_type(4))) float  f32x4;

#if __has_builtin(__builtin_amdgcn_sqrtf)
#define FSQRT(x) __builtin_amdgcn_sqrtf(x)
#else
#define FSQRT(x) sqrtf(x)
#endif
#if __has_builtin(__builtin_amdgcn_rcpf)
#define FRCP(x) __builtin_amdgcn_rcpf(x)
#else
#define FRCP(x) (1.0f / (x))
#endif
#if __has_builtin(__builtin_amdgcn_fmed3f)
#define FCLAMP(x) __builtin_amdgcn_fmed3f((x), 0.0f, MARGINP2)
#else
#define FCLAMP(x) fminf(fmaxf((x), 0.0f), MARGINP2)
#endif

__device__ __forceinline__ unsigned short f2bf(float x) {
  unsigned u = __float_as_uint(x);            // RTNE bf16, inputs finite
  return (unsigned short)((u + 0x7FFFu + ((u >> 16) & 1u)) >> 16);
}

// Wave handles 4 rows (16 lanes/row, 8 floats/lane): bf16 convert + sumsq + label mask.
__global__ void prep_kernel(const float* __restrict__ feat, const int* __restrict__ label,
                            unsigned short* __restrict__ fbf, float* __restrict__ sq,
                            int* __restrict__ maskA) {
  int wv = threadIdx.x >> 6, lane = threadIdx.x & 63;
  int sub = lane >> 4, l16 = lane & 15;
  int row = blockIdx.x * 16 + wv * 4 + sub;
  const float* rp = feat + (size_t)row * MDIM + l16 * 8;
  float4 va = *reinterpret_cast<const float4*>(rp);
  float4 vb = *reinterpret_cast<const float4*>(rp + 4);
  s16x8 st;
  st[0]=(short)f2bf(va.x); st[1]=(short)f2bf(va.y); st[2]=(short)f2bf(va.z); st[3]=(short)f2bf(va.w);
  st[4]=(short)f2bf(vb.x); st[5]=(short)f2bf(vb.y); st[6]=(short)f2bf(vb.z); st[7]=(short)f2bf(vb.w);
  *reinterpret_cast<s16x8*>(fbf + (size_t)row * MDIM + l16 * 8) = st;
  float s = va.x*va.x + va.y*va.y + va.z*va.z + va.w*va.w
          + vb.x*vb.x + vb.y*vb.y + vb.z*vb.z + vb.w*vb.w;
  #pragma unroll
  for (int off = 8; off >= 1; off >>= 1) s += __shfl_xor(s, off);   // reduce within 16-lane row group
  int lab = label[((size_t)blockIdx.x * 16 + wv * 4) * KLAB + lane];
  unsigned long long bal = __ballot(lab > 0);
  if (l16 == 0) {
    sq[row]    = s;
    maskA[row] = (int)(unsigned)((bal >> (sub * 16)) & 0xFFFFull);
  }
}

// Block = 4 waves (2x2 grid) = one 64x128 half-tile of a 128x128 supertile (bi<=bj).
// B slab (32 KB) in LDS, XOR-swizzled; A fragments direct from global (once, L2-resident).
// 4 blocks/CU in independent phases -> stage/barrier of one hides under compute of others.
// mfma_f32_16x16x32_bf16 layout as verified in round 2 (absmax == 0).
__global__ __launch_bounds__(256, 4) void pair_main(
    const unsigned short* __restrict__ fbf, const float* __restrict__ sq,
    const int* __restrict__ maskA, float* __restrict__ part) {
  __shared__ char smem[32768];            // B slab
  __shared__ float bsum[4];

  // XCD swizzle: 4160 = 8 x 520, consecutive same-bi tiles share an XCD's L2
  int orig = blockIdx.x;
  int swz = (orig & 7) * (NBLK / 8) + (orig >> 3);
  int sid = swz >> 1, half = swz & 1;

  int bi = 0, rem = sid;
  while (rem >= NSLAB - bi) { rem -= NSLAB - bi; bi++; }
  int bj = bi + rem;
  bool diag = (bi == bj);

  int wv = threadIdx.x >> 6, lane = threadIdx.x & 63;
  int l15 = lane & 15, lg = lane >> 4;
  int wr = wv >> 1, wc = wv & 1;          // 2x2 wave grid: 32 rows x 64 cols each

  const char* fb = (const char*)fbf;
  int arow = bi * 128 + half * 64 + wr * 32;

  // ---- A fragments direct from global, issued first so they fly under B staging ----
  s16x8 af[2][4];
  #pragma unroll
  for (int fi = 0; fi < 2; fi++)
    #pragma unroll
    for (int ks = 0; ks < 4; ks++)
      af[fi][ks] = *reinterpret_cast<const s16x8*>(
          fb + (size_t)(arow + fi * 16 + l15) * 256 + ks * 64 + lg * 16);

  // ---- metadata (L2-resident 32KB arrays) ----
  float sqi[2][4]; int mi[2][4];
  #pragma unroll
  for (int fi = 0; fi < 2; fi++)
    #pragma unroll
    for (int r = 0; r < 4; r++) {
      int ir = arow + fi * 16 + lg * 4 + r;           // C/D row = lg*4 + r
      sqi[fi][r] = sq[ir]; mi[fi][r] = maskA[ir];
    }
  float sqj[4]; int mj[4];
  #pragma unroll
  for (int fj = 0; fj < 4; fj++) {
    int jr = bj * 128 + wc * 64 + fj * 16 + l15;      // C/D col = l15
    sqj[fj] = sq[jr]; mj[fj] = maskA[jr];
  }

  // ---- stage B slab: coalesced 16B/thread x8 -> swizzled ds_write_b128 ----
  {
    const char* gB = fb + (size_t)bj * 128 * 256;
    #pragma unroll
    for (int k = 0; k < 8; k++) {
      int f = threadIdx.x + 256 * k;                  // linear 16B-chunk index
      int row = f >> 4, c = f & 15;
      s16x8 v = *reinterpret_cast<const s16x8*>(gB + row * 256 + c * 16);
      int wck = c ^ (row & 7);                        // XOR swizzle on 16B chunk index
      *reinterpret_cast<s16x8*>(smem + row * 256 + wck * 16) = v;
    }
  }
  __syncthreads();

  float sum = 0.0f;

  #pragma unroll
  for (int fj = 0; fj < 4; fj++) {
    s16x8 B[4];
    #pragma unroll
    for (int ks = 0; ks < 4; ks++) {
      int lr = wc * 64 + fj * 16 + l15;
      int rc = (ks * 4 + lg) ^ (lr & 7);
      B[ks] = *reinterpret_cast<const s16x8*>(smem + lr * 256 + rc * 16);
    }

    f32x4 acc[2];
    acc[0] = (f32x4){0.f,0.f,0.f,0.f}; acc[1] = (f32x4){0.f,0.f,0.f,0.f};
    #pragma unroll
    for (int ks = 0; ks < 4; ks++)
      #pragma unroll
      for (int fi = 0; fi < 2; fi++)
        acc[fi] = __builtin_amdgcn_mfma_f32_16x16x32_bf16(af[fi][ks], B[ks], acc[fi], 0, 0, 0);

    #pragma unroll
    for (int fi = 0; fi < 2; fi++)
      #pragma unroll
      for (int r = 0; r < 4; r++) {
        float g  = acc[fi][r];
        float d2 = fmaf(-2.0f, g, sqi[fi][r] + sqj[fj]);
        float t  = FSQRT(FCLAMP(d2));
        int inter = __popc(mi[fi][r] & mj[fj]);
        int uni   = __popc(mi[fi][r] | mj[fj]);
        float w = (float)inter * FRCP((float)uni);
        w = (inter == 0) ? -1.0f : w;
        if (diag) {
          int il = half * 64 + wr * 32 + fi * 16 + lg * 4 + r;   // local row in supertile
          int jl = wc * 64 + fj * 16 + l15;                      // local col in supertile
          w *= (jl > il) ? 2.0f : ((jl == il) ? 1.0f : 0.0f);
        }
        sum = fmaf(w, t, sum);
      }
  }

  #pragma unroll
  for (int off = 32; off >= 1; off >>= 1) sum += __shfl_xor(sum, off);
  if (lane == 0) bsum[wv] = sum;
  __syncthreads();
  if (threadIdx.x == 0) {
    float s = bsum[0] + bsum[1] + bsum[2] + bsum[3];
    part[orig] = diag ? s : 2.0f * s;     // one plain store per block
  }
}

// Single block: sum 4160 partials (double accum) + apply deferred scales.
__global__ void reduce_kernel(const float* __restrict__ part, float* __restrict__ out) {
  int tid = threadIdx.x;
  double s = 0.0;
  for (int i = tid; i < NBLK; i += 256) s += (double)part[i];
  #pragma unroll
  for (int off = 32; off >= 1; off >>= 1) s += __shfl_xor(s, off);
  __shared__ double wsum[4];
  int wv = tid >> 6, lane = tid & 63;
  if (lane == 0) wsum[wv] = s;
  __syncthreads();
  if (tid == 0) {
    double t = wsum[0] + wsum[1] + wsum[2] + wsum[3];
    // undo deferred scales: /sqrt(128) and /n^2
    out[0] = (float)(t * (1.0 / (11.313708498984760 * 67108864.0)));
  }
}

extern "C" void kernel_launch(void* const* d_in, const int* in_sizes, int n_in,
                              void* d_out, int out_size, void* d_ws, size_t ws_size,
                              hipStream_t stream) {
  const float* feat  = (const float*)d_in[0];
  const int*   label = (const int*)d_in[1];
  char* ws = (char*)d_ws;
  float* part           = (float*)ws;                            // 4160 floats (16896 B reserved)
  float* sq             = (float*)(ws + 16896);                  // 32 KB
  int*   maskA          = (int*)(ws + 16896 + 32768);            // 32 KB
  unsigned short* fbf   = (unsigned short*)(ws + 16896 + 65536); // 2 MB bf16 feature
  float* out = (float*)d_out;

  prep_kernel<<<NROW / 16, 256, 0, stream>>>(feat, label, fbf, sq, maskA);
  pair_main<<<NBLK, 256, 0, stream>>>(fbf, sq, maskA, part);
  reduce_kernel<<<1, 256, 0, stream>>>(part, out);
}